// Round 18
// baseline (108.271 us; speedup 1.0000x reference)
//
#include <hip/hip_runtime.h>

// Problem: H=W=384, F=K=256. M = 147456 rows.
// out[m,f] = sum_k d[m,k] * y[k,f],  y = x[stations] @ W  (256x256, tiny)
#define FF 256
#define KK 256
#define MROWS 147456
// ---- two-phase path ----
#define NPACK 4608             // 32-row groups
#define NB2 2304               // gemm2 blocks (x4 waves; wave=32 cols x 128 rows)
// ---- fallback (R13) path ----
#define RR 16
#define STRIPES 4
#define NBLK 4608
#define HALFC 128

typedef __attribute__((ext_vector_type(8)))  short bf16x8;   // 8 bf16 (4 VGPR)
typedef __attribute__((ext_vector_type(4)))  float f32x4;
typedef __attribute__((ext_vector_type(16))) float f32x16;   // 32x32 acc
typedef __attribute__((ext_vector_type(4)))  short short4v;

__device__ inline short f2bf(float x) {
    unsigned u = __float_as_uint(x);
    unsigned r = u + 0x7FFFu + ((u >> 16) & 1u);
    return (short)(r >> 16);
}

// Kernel 1: y[k][f] = sum_j x[..]*W[j][f]; writes BOTH layouts:
//  yp : 16x16x32 fragment order (fallback path)
//  yp2: 32x32x16 B-fragment order: ((f>>5)*16 + (k>>4))*512
//       + (((k>>3)&1)*32 + (f&31))*8 + (k&7)
__global__ __launch_bounds__(256) void station_kernel(
        const float* __restrict__ x, const float* __restrict__ W,
        const int* __restrict__ sx, const int* __restrict__ sy,
        short* __restrict__ yp, short* __restrict__ yp2, int writeBoth) {
    __shared__ float xrow[FF];
    const int k = blockIdx.x;
    const int f = threadIdx.x;
    const long base = ((long)sx[k] * 384 + (long)sy[k]) * FF;
    xrow[f] = x[base + f];
    __syncthreads();
    float acc = 0.f;
    #pragma unroll 8
    for (int j = 0; j < FF; ++j)
        acc += xrow[j] * W[j * FF + f];
    const short v = f2bf(acc);
    const int idx = ((f >> 4) * 8 + (k >> 5)) * 512
                  + (((k >> 3) & 3) * 16 + (f & 15)) * 8 + (k & 7);
    yp[idx] = v;
    if (writeBoth) {
        const int i2 = ((f >> 5) * 16 + (k >> 4)) * 512
                     + (((k >> 3) & 1) * 32 + (f & 31)) * 8 + (k & 7);
        yp2[i2] = v;
    }
}

// Phase 1: stream-transpose d -> packed bf16 A-fragments (32x32x16 layout):
// packA[grp*8192 + kt*512 + lane*8 + j] = bf16(d[grp*32 + (lane&31)]
//                                               [kt*16 + (lane>>5)*8 + j])
// Both global sides >=1KB contiguous per wave-instruction.
// FIX vs R17: 8 staging passes (8*256*4 = 8192 floats = full 32-row tile;
// R17 had 2 passes -> rows 8..31 were garbage -> absmax 101).
__global__ __launch_bounds__(256) void pack_kernel(
        const float* __restrict__ dIn, short* __restrict__ packA) {
    __shared__ __align__(16) short lt[32 * KK];   // 16 KB, XOR-swizzled
    const int t    = threadIdx.x;
    const int lane = t & 63;
    const int wv   = t >> 6;
    // XCD swizzle matched to gemm2's rt ranges: XCD x packs grp [x*576,..)
    const int grp = (blockIdx.x & 7) * (NPACK / 8) + (blockIdx.x >> 3);

    const float* dp = dIn + (size_t)grp * 32 * KK;
    char* lb = (char*)lt;
    #pragma unroll
    for (int p = 0; p < 8; ++p) {
        const int idx = p * 1024 + t * 4;         // float index (0..8191)
        float4 v = *(const float4*)(dp + idx);
        const int row  = idx >> 8;                // 0..31
        const int colb = (idx & 255) * 2;         // byte col 0..510
        const int byte = row * 512 + (colb ^ ((row & 31) << 4));
        short4v b;
        b.x = f2bf(v.x); b.y = f2bf(v.y); b.z = f2bf(v.z); b.w = f2bf(v.w);
        *(short4v*)(lb + byte) = b;
    }
    __syncthreads();
    short* op = packA + (size_t)grp * 8192;
    #pragma unroll
    for (int i = 0; i < 4; ++i) {
        const int kt   = wv * 4 + i;
        const int row  = lane & 31;
        const int colb = (kt * 16 + ((lane >> 5) * 8)) * 2;
        const int byte = row * 512 + (colb ^ ((row & 31) << 4));
        bf16x8 a = *(const bf16x8*)(lb + byte);
        *(bf16x8*)(op + kt * 512 + (lane << 3)) = a;   // 1KB/instr contiguous
    }
}

// Phase 2: barrier-free, LDS-free GEMM on 32x32x16 MFMA.
// Wave owns 32 cols (bfrag[16] pinned resident) x 128 rows (4 rt-tiles).
// A-frag loads: 1KB contiguous/instr from packA (L3-hot, 75.5 MB).
// C-stores: per instr 2 x 128B full cache lines (aligned).
__global__ __launch_bounds__(256, 3) void gemm2_kernel(
        const short* __restrict__ packA, const short* __restrict__ yp2,
        float* __restrict__ out) {
    const int t    = threadIdx.x;
    const int lane = t & 63;
    const int wid  = t >> 6;
    // bijective XCD swizzle (NB2 % 8 == 0)
    const int work   = (blockIdx.x & 7) * (NB2 / 8) + (blockIdx.x >> 3);
    const int g32    = wid * 2 + (work & 1);     // 0..7: 32-col slice
    const int rgroup = work >> 1;                // 0..1151

    // ---- B fragments: 16 x 1KB coalesced loads, pinned resident ----
    bf16x8 bfrag[16];
    #pragma unroll
    for (int kt = 0; kt < 16; ++kt)
        bfrag[kt] = *(const bf16x8*)(yp2 + (g32 * 16 + kt) * 512 + (lane << 3));
    asm volatile("" :
        "+v"(bfrag[0]),  "+v"(bfrag[1]),  "+v"(bfrag[2]),  "+v"(bfrag[3]),
        "+v"(bfrag[4]),  "+v"(bfrag[5]),  "+v"(bfrag[6]),  "+v"(bfrag[7]),
        "+v"(bfrag[8]),  "+v"(bfrag[9]),  "+v"(bfrag[10]), "+v"(bfrag[11]),
        "+v"(bfrag[12]), "+v"(bfrag[13]), "+v"(bfrag[14]), "+v"(bfrag[15]));

    const int row5 = 4 * (lane >> 5);            // C row offset term
    const int c31  = lane & 31;

    #pragma unroll
    for (int it = 0; it < 4; ++it) {
        const int rt = rgroup * 4 + it;
        const short* ap = packA + (size_t)rt * 8192 + (lane << 3);

        f32x16 acc;
        #pragma unroll
        for (int q = 0; q < 16; ++q) acc[q] = 0.f;

        bf16x8 af[8];
        #pragma unroll
        for (int kt = 0; kt < 8; ++kt)
            af[kt] = *(const bf16x8*)(ap + kt * 512);
        #pragma unroll
        for (int kt = 0; kt < 8; ++kt)
            acc = __builtin_amdgcn_mfma_f32_32x32x16_bf16(
                      af[kt], bfrag[kt], acc, 0, 0, 0);
        #pragma unroll
        for (int kt = 0; kt < 8; ++kt)
            af[kt] = *(const bf16x8*)(ap + (8 + kt) * 512);
        #pragma unroll
        for (int kt = 0; kt < 8; ++kt)
            acc = __builtin_amdgcn_mfma_f32_32x32x16_bf16(
                      af[kt], bfrag[8 + kt], acc, 0, 0, 0);

        // C store: row=(r&3)+8*(r>>2)+row5, col=g32*32+c31 (2 lines/instr)
        float* ob = out + (size_t)rt * 32 * FF + g32 * 32;
        #pragma unroll
        for (int r = 0; r < 16; ++r)
            ob[(size_t)((r & 3) + 8 * (r >> 2) + row5) * FF + c31] = acc[r];
    }
}

// -------- fallback: round-13 kernel (proven 77.6 us) --------
__global__ __launch_bounds__(256, 4) void gemm_kernel(
        const float* __restrict__ d, const short* __restrict__ yp,
        float* __restrict__ out) {
    __shared__ __align__(16) short ldsA[2][RR * KK];
    __shared__ __align__(16) float ldsC[RR * HALFC];
    const int t    = threadIdx.x;
    const int lane = t & 63;
    const int wid  = t >> 6;
    const int l15  = lane & 15;
    const int lg   = lane >> 4;
    const int work = (blockIdx.x & 7) * (NBLK / 8) + (blockIdx.x >> 3);
    const int half = work & 1;
    const long mblk = (long)(work >> 1) * (RR * STRIPES);
    char* lb0 = (char*)ldsA[0];
    char* lb1 = (char*)ldsA[1];
    bf16x8 bfrag[8][2];
    #pragma unroll
    for (int kf = 0; kf < 8; ++kf)
        #pragma unroll
        for (int nf = 0; nf < 2; ++nf) {
            const int g = half * 8 + wid * 2 + nf;
            bfrag[kf][nf] = *(const bf16x8*)(yp + ((g * 8 + kf) << 9) + (lane << 3));
        }
    asm volatile("" :
        "+v"(bfrag[0][0]), "+v"(bfrag[0][1]), "+v"(bfrag[1][0]), "+v"(bfrag[1][1]),
        "+v"(bfrag[2][0]), "+v"(bfrag[2][1]), "+v"(bfrag[3][0]), "+v"(bfrag[3][1]),
        "+v"(bfrag[4][0]), "+v"(bfrag[4][1]), "+v"(bfrag[5][0]), "+v"(bfrag[5][1]),
        "+v"(bfrag[6][0]), "+v"(bfrag[6][1]), "+v"(bfrag[7][0]), "+v"(bfrag[7][1]));
    const int srow0 = t >> 6;
    const int scol  = (t & 63) * 8;
    float4 pv[4];
    {
        const float* dp = d + mblk * KK;
        #pragma unroll
        for (int p = 0; p < 4; ++p)
            pv[p] = *(const float4*)(dp + (p * 256 + t) * 4);
        #pragma unroll
        for (int p = 0; p < 4; ++p) {
            const int row = p * 4 + srow0;
            int byte = row * 512 + scol;
            byte ^= (row & 7) << 4;
            short4v b;
            b.x = f2bf(pv[p].x); b.y = f2bf(pv[p].y);
            b.z = f2bf(pv[p].z); b.w = f2bf(pv[p].w);
            *(short4v*)(lb0 + byte) = b;
        }
    }
    __syncthreads();
    for (int s = 0; s < STRIPES; ++s) {
        const long m0 = mblk + (long)s * RR;
        char* cur = (s & 1) ? lb1 : lb0;
        char* nxt = (s & 1) ? lb0 : lb1;
        if (s + 1 < STRIPES) {
            const float* dp = d + (m0 + RR) * KK;
            #pragma unroll
            for (int p = 0; p < 4; ++p)
                pv[p] = *(const float4*)(dp + (p * 256 + t) * 4);
        }
        f32x4 acc[2];
        #pragma unroll
        for (int nf = 0; nf < 2; ++nf)
            #pragma unroll
            for (int q = 0; q < 4; ++q) acc[nf][q] = 0.f;
        #pragma unroll
        for (int kf = 0; kf < 8; ++kf) {
            const int cb = kf * 64 + lg * 16;
            const int xo = (l15 & 7) << 4;
            bf16x8 a0 = *(const bf16x8*)(cur + ((l15 * 512 + cb) ^ xo));
            #pragma unroll
            for (int nf = 0; nf < 2; ++nf)
                acc[nf] = __builtin_amdgcn_mfma_f32_16x16x32_bf16(
                              a0, bfrag[kf][nf], acc[nf], 0, 0, 0);
        }
        #pragma unroll
        for (int nf = 0; nf < 2; ++nf)
            #pragma unroll
            for (int q = 0; q < 4; ++q)
                ldsC[(lg * 4 + q) * HALFC + wid * 32 + nf * 16 + l15]
                    = acc[nf][q];
        __syncthreads();
        #pragma unroll
        for (int p = 0; p < 2; ++p) {
            const int e = p * 1024 + t * 4;
            const float4 v = *(const float4*)(ldsC + e);
            *(float4*)(out + (m0 + (e >> 7)) * FF + half * HALFC + (e & 127)) = v;
        }
        if (s + 1 < STRIPES) {
            #pragma unroll
            for (int p = 0; p < 4; ++p) {
                const int row = p * 4 + srow0;
                int byte = row * 512 + scol;
                byte ^= (row & 7) << 4;
                short4v b;
                b.x = f2bf(pv[p].x); b.y = f2bf(pv[p].y);
                b.z = f2bf(pv[p].z); b.w = f2bf(pv[p].w);
                *(short4v*)(nxt + byte) = b;
            }
        }
        __syncthreads();
    }
}

extern "C" void kernel_launch(void* const* d_in, const int* in_sizes, int n_in,
                              void* d_out, int out_size, void* d_ws, size_t ws_size,
                              hipStream_t stream) {
    const float* x    = (const float*)d_in[0];
    const float* dmat = (const float*)d_in[1];
    const float* W    = (const float*)d_in[2];
    const int*   sx   = (const int*)d_in[3];
    const int*   sy   = (const int*)d_in[4];
    float* out = (float*)d_out;
    short* yp    = (short*)d_ws;          // 128 KB (16x16 frag order)
    short* yp2   = yp + 65536;            // 128 KB (32x32 B-frag order)
    short* packA = yp2 + 65536;           // 75.5 MB packed A fragments

    const size_t need = 262144 + (size_t)MROWS * KK * 2;
    const int big = (ws_size >= need) ? 1 : 0;

    station_kernel<<<dim3(KK), dim3(FF), 0, stream>>>(x, W, sx, sy, yp, yp2, big);
    if (big) {
        pack_kernel<<<dim3(NPACK), dim3(256), 0, stream>>>(dmat, packA);
        gemm2_kernel<<<dim3(NB2), dim3(256), 0, stream>>>(packA, yp2, out);
    } else {
        gemm_kernel<<<dim3(NBLK), dim3(256), 0, stream>>>(dmat, yp, out);
    }
}